// Round 1
// baseline (418.884 us; speedup 1.0000x reference)
//
#include <hip/hip_runtime.h>

// TriangleAttention (starting node), MI355X gfx950.
// B=1, N=320, DIM=128, HEADS=4, DH=64, INNER=256. All fp32 I/O, bf16 MFMA inside.
//
// Kernel 0: attn_bias[h][k][q] = sum_d pairwise[q,k,d]*Wbias[d,h]  (global (q,k) bias!)
// Kernel A: per (head h, row i): qkv projection + full softmax attention, fused in LDS.
//           All MFMA D-outputs ds_write_b64-packed into layouts that read back as
//           contiguous ds_read_b128 A/B fragments (K^T/Q^T orientation for K/Q, natural
//           for V; scores transposed so softmax is lane-local + shfl_xor(32); P stays
//           in registers, PV B-frags built via shfl_xor(32)).
// Kernel B: out = Attn[102400x256]bf16 @ Wout[256x128] + bout  (bias in acc init).

#define NN     320
#define DIMD   128
#define NHEADS 4
#define DH     64
#define INNERD 256
#define NPAIR  (NN*NN)
#define SCALE  0.125f

typedef __attribute__((ext_vector_type(8)))  short    bf16x8;  // 8 bf16 = 4 VGPRs
typedef __attribute__((ext_vector_type(16))) float    f32x16;  // 32x32 C/D
typedef __attribute__((ext_vector_type(4)))  unsigned u32x4;

#define MFMA32(a,b,c) __builtin_amdgcn_mfma_f32_32x32x16_bf16((a),(b),(c),0,0,0)

__device__ __forceinline__ unsigned pkbf(float lo, float hi){
  // pack two fp32 -> two bf16 (RNE) in one dword
  unsigned a = __builtin_bit_cast(unsigned, lo);
  unsigned b = __builtin_bit_cast(unsigned, hi);
  a = (a + 0x7fffu + ((a>>16)&1u)) >> 16;
  b = (b + 0x7fffu + ((b>>16)&1u)) >> 16;
  return (a & 0xffffu) | (b<<16);
}

__device__ __forceinline__ f32x16 z16(){
  f32x16 v;
#pragma unroll
  for (int k = 0; k < 16; ++k) v[k] = 0.0f;
  return v;
}

// ---------------------------------------------------------------------------
// Kernel 0: bias.  One WG per query row q. Bws layout [h][k][q] (q contiguous
// so kernel A's per-register loads coalesce across lanes).
// ---------------------------------------------------------------------------
__global__ void __launch_bounds__(256) bias_kernel(const float* __restrict__ X,
                                                   const float* __restrict__ Wbias,
                                                   float* __restrict__ Bws){
  __shared__ float part[64][4][4];           // [krow][seg][h]
  const int q = blockIdx.x;
  const int t = threadIdx.x;
  const int krow = t & 63, seg = t >> 6;
  for (int kk = 0; kk < NN; kk += 64){
    const int k = kk + krow;                 // 320 % 64 == 0 -> always valid
    float sx=0.f, sy=0.f, sz=0.f, sw=0.f;
    {
      const float4* xr = (const float4*)(X + ((size_t)q*NN + k)*DIMD + seg*32);
      const float4* wb = (const float4*)(Wbias + seg*32*4);
#pragma unroll
      for (int d4 = 0; d4 < 8; ++d4){
        float4 x  = xr[d4];
        float4 w0 = wb[d4*4+0], w1 = wb[d4*4+1], w2 = wb[d4*4+2], w3 = wb[d4*4+3];
        sx += x.x*w0.x + x.y*w1.x + x.z*w2.x + x.w*w3.x;
        sy += x.x*w0.y + x.y*w1.y + x.z*w2.y + x.w*w3.y;
        sz += x.x*w0.z + x.y*w1.z + x.z*w2.z + x.w*w3.z;
        sw += x.x*w0.w + x.y*w1.w + x.z*w2.w + x.w*w3.w;
      }
    }
    part[krow][seg][0]=sx; part[krow][seg][1]=sy; part[krow][seg][2]=sz; part[krow][seg][3]=sw;
    __syncthreads();
    if (t < 64){
      const int kg = kk + t;
#pragma unroll
      for (int hh = 0; hh < 4; ++hh){
        float v = part[t][0][hh] + part[t][1][hh] + part[t][2][hh] + part[t][3][hh];
        Bws[((size_t)hh*NN + kg)*NN + q] = v;
      }
    }
    __syncthreads();
  }
}

// ---------------------------------------------------------------------------
// Kernel A: fused qkv + attention per (h, i).  256 threads = 4 waves, 1 WG/CU.
// LDS map (bytes):
//   K   [320 j][64 d]  bf16, row stride 144   :      0 .. 46080
//   Vt  [64 d][320 j]  bf16, row stride 656   :  46080 .. 88064
//   Wqt [64 col][128 d]bf16, row stride 272   :  88064 .. 105472
//   R1  (34816): phase1 = Wk/Wv cols 64..191 (stride 272); phase2 = X2 128 rows (272)
//   R2  (18432): phase1 = X1 64 rows (272);   phase2 = Q 128 rows (stride 144)
// ---------------------------------------------------------------------------
#define KOFF   0
#define VTOFF  46080
#define WQOFF  88064
#define R1OFF  105472
#define R2OFF  140288
#define LDS_A  158720
#define KSTR   144
#define QSTR   144
#define VTSTR  656
#define XSTR   272
#define WSTR   272

__global__ void __launch_bounds__(256, 1) attn_kernel(const float* __restrict__ X,
                                                      const float* __restrict__ Wqkv,
                                                      const float* __restrict__ Bws,
                                                      unsigned short* __restrict__ AttnOut){
  extern __shared__ char sm[];
  const int h = blockIdx.x, i = blockIdx.y;
  const int tid  = threadIdx.x;
  const int w    = tid >> 6;
  const int lane = tid & 63;
  const int half = lane >> 5;
  const int l31  = lane & 31;
  const int coff = half*16;                  // byte offset of this half's 8-elem k-chunk
  const float* Xi = X + (size_t)i * NN * DIMD;

  // ---- stage W^T slices (transposed to [col][din] so both A- and B-frags are b128)
  if (tid < 192){
    const int col  = tid;
    const int gcol = (col < 64)  ? (h*DH + col)
                   : (col < 128) ? (INNERD   + h*DH + (col-64))
                                 : (2*INNERD + h*DH + (col-128));
    char* dst = (col < 64) ? (sm + WQOFF + col*WSTR) : (sm + R1OFF + (col-64)*WSTR);
    for (int d0 = 0; d0 < DIMD; d0 += 8){
      unsigned p0 = pkbf(Wqkv[(size_t)(d0+0)*768 + gcol], Wqkv[(size_t)(d0+1)*768 + gcol]);
      unsigned p1 = pkbf(Wqkv[(size_t)(d0+2)*768 + gcol], Wqkv[(size_t)(d0+3)*768 + gcol]);
      unsigned p2 = pkbf(Wqkv[(size_t)(d0+4)*768 + gcol], Wqkv[(size_t)(d0+5)*768 + gcol]);
      unsigned p3 = pkbf(Wqkv[(size_t)(d0+6)*768 + gcol], Wqkv[(size_t)(d0+7)*768 + gcol]);
      u32x4 v; v[0]=p0; v[1]=p1; v[2]=p2; v[3]=p3;
      *(u32x4*)(dst + d0*2) = v;
    }
  }

  // ================= phase 1: K and V for all 320 keys =================
  for (int jb = 0; jb < 5; ++jb){
    __syncthreads();                         // protect X1/Wt from prior readers
    {
      const float4* src = (const float4*)(Xi + (size_t)(jb*64)*DIMD);
      for (int idx = tid; idx < 64*DIMD/4; idx += 256){
        float4 x = src[idx];
        int e = idx*4, row = e >> 7, dp = e & 127;
        uint2 v; v.x = pkbf(x.x,x.y); v.y = pkbf(x.z,x.w);
        *(uint2*)(sm + R2OFF + row*XSTR + dp*2) = v;
      }
    }
    __syncthreads();
    {
      f32x16 acc0 = z16(), acc1 = z16();
      const bool isK = (w < 2);
      const int  mt  = w & 1;
      const char *Ab, *Bb0, *Bb1;
      if (isK){ // K^T = Wk^T @ X^T : D col = j, rows = d  -> b64 writes into K[j][d]
        Ab  = sm + R1OFF + (size_t)(mt*32 + l31)*WSTR;      // Wk col (R1 idx 0..63)
        Bb0 = sm + R2OFF + (size_t)(l31)*XSTR;
        Bb1 = sm + R2OFF + (size_t)(32 + l31)*XSTR;
      } else {  // V = X @ Wv : D col = dout, rows = j     -> b64 writes into Vt[d][j]
        Ab  = sm + R2OFF + (size_t)(mt*32 + l31)*XSTR;
        Bb0 = sm + R1OFF + (size_t)(64 + l31)*WSTR;         // Wv col (R1 idx 64..127)
        Bb1 = sm + R1OFF + (size_t)(96 + l31)*WSTR;
      }
#pragma unroll
      for (int ks = 0; ks < 8; ++ks){
        bf16x8 a  = *(const bf16x8*)(Ab  + ks*32 + coff);
        bf16x8 b0 = *(const bf16x8*)(Bb0 + ks*32 + coff);
        bf16x8 b1 = *(const bf16x8*)(Bb1 + ks*32 + coff);
        acc0 = MFMA32(a, b0, acc0);
        acc1 = MFMA32(a, b1, acc1);
      }
      if (isK){
#pragma unroll
        for (int rq = 0; rq < 4; ++rq){
          const int dd = mt*32 + 8*rq + 4*half;
          uint2 v0, v1;
          v0.x = pkbf(acc0[4*rq+0], acc0[4*rq+1]); v0.y = pkbf(acc0[4*rq+2], acc0[4*rq+3]);
          v1.x = pkbf(acc1[4*rq+0], acc1[4*rq+1]); v1.y = pkbf(acc1[4*rq+2], acc1[4*rq+3]);
          *(uint2*)(sm + KOFF + (size_t)(jb*64 +      l31)*KSTR + dd*2) = v0;
          *(uint2*)(sm + KOFF + (size_t)(jb*64 + 32 + l31)*KSTR + dd*2) = v1;
        }
      } else {
#pragma unroll
        for (int rq = 0; rq < 4; ++rq){
          const int jj = jb*64 + mt*32 + 8*rq + 4*half;
          uint2 v0, v1;
          v0.x = pkbf(acc0[4*rq+0], acc0[4*rq+1]); v0.y = pkbf(acc0[4*rq+2], acc0[4*rq+3]);
          v1.x = pkbf(acc1[4*rq+0], acc1[4*rq+1]); v1.y = pkbf(acc1[4*rq+2], acc1[4*rq+3]);
          *(uint2*)(sm + VTOFF + (size_t)(     l31)*VTSTR + jj*2) = v0;
          *(uint2*)(sm + VTOFF + (size_t)(32 + l31)*VTSTR + jj*2) = v1;
        }
      }
    }
  }

  // ================= phase 2: Q, scores^T, softmax, PV =================
  for (int qb = 0; qb < 3; ++qb){
    const int q0 = qb*128;
    const int nr = (NN - q0 < 128) ? (NN - q0) : 128;
    __syncthreads();                         // protect X2(R1)/Q(R2) regions
    {
      const float4* src = (const float4*)(Xi + (size_t)q0*DIMD);
      const int tot = nr*DIMD/4;
      for (int idx = tid; idx < tot; idx += 256){
        float4 x = src[idx];
        int e = idx*4, row = e >> 7, dp = e & 127;
        uint2 v; v.x = pkbf(x.x,x.y); v.y = pkbf(x.z,x.w);
        *(uint2*)(sm + R1OFF + row*XSTR + dp*2) = v;
      }
    }
    __syncthreads();
    const int q0w = q0 + w*32;
    if (q0w < NN){
      // ---- Q^T = Wq^T @ X^T : D col = q (this wave's 32 rows), rows = d
      {
        f32x16 qa0 = z16(), qa1 = z16();
        const char* Bb = sm + R1OFF + (size_t)(w*32 + l31)*XSTR;
#pragma unroll
        for (int ks = 0; ks < 8; ++ks){
          bf16x8 b  = *(const bf16x8*)(Bb + ks*32 + coff);
          bf16x8 a0 = *(const bf16x8*)(sm + WQOFF + (size_t)(     l31)*WSTR + ks*32 + coff);
          bf16x8 a1 = *(const bf16x8*)(sm + WQOFF + (size_t)(32 + l31)*WSTR + ks*32 + coff);
          qa0 = MFMA32(a0, b, qa0);
          qa1 = MFMA32(a1, b, qa1);
        }
#pragma unroll
        for (int rq = 0; rq < 4; ++rq){
          const int dd = 8*rq + 4*half;
          uint2 v0, v1;
          v0.x = pkbf(qa0[4*rq+0], qa0[4*rq+1]); v0.y = pkbf(qa0[4*rq+2], qa0[4*rq+3]);
          v1.x = pkbf(qa1[4*rq+0], qa1[4*rq+1]); v1.y = pkbf(qa1[4*rq+2], qa1[4*rq+3]);
          *(uint2*)(sm + R2OFF + (size_t)(w*32 + l31)*QSTR + dd*2)      = v0;
          *(uint2*)(sm + R2OFF + (size_t)(w*32 + l31)*QSTR + (32+dd)*2) = v1;
        }
      }
      // ---- scores^T: S[j][q] = K[j]·Q[q];  D col = q = l31, rows = j
      bf16x8 qf[4];
#pragma unroll
      for (int ks = 0; ks < 4; ++ks)
        qf[ks] = *(const bf16x8*)(sm + R2OFF + (size_t)(w*32 + l31)*QSTR + ks*32 + coff);
      f32x16 S[10];
#pragma unroll
      for (int jt = 0; jt < 10; ++jt) S[jt] = z16();
#pragma unroll
      for (int jt = 0; jt < 10; ++jt){
#pragma unroll
        for (int ks = 0; ks < 4; ++ks){
          bf16x8 a = *(const bf16x8*)(sm + KOFF + (size_t)(jt*32 + l31)*KSTR + ks*32 + coff);
          S[jt] = MFMA32(a, qf[ks], S[jt]);
        }
      }
      // ---- scale + (q,k)-bias + softmax over j (my lane holds half the j's; xor-32 merges)
      const float* Bh = Bws + (size_t)h*NN*NN + (q0w + l31);
      float m = -3.0e38f;
#pragma unroll
      for (int jt = 0; jt < 10; ++jt){
#pragma unroll
        for (int rq = 0; rq < 4; ++rq){
          const int jj = jt*32 + 8*rq + 4*half;
#pragma unroll
          for (int r = 0; r < 4; ++r){
            float v = S[jt][4*rq+r]*SCALE + Bh[(size_t)(jj+r)*NN];
            S[jt][4*rq+r] = v;
            m = fmaxf(m, v);
          }
        }
      }
      m = fmaxf(m, __shfl_xor(m, 32));
      float l = 0.0f;
#pragma unroll
      for (int jt = 0; jt < 10; ++jt){
#pragma unroll
        for (int k = 0; k < 16; ++k){
          float e = __expf(S[jt][k] - m);
          S[jt][k] = e;
          l += e;
        }
      }
      l += __shfl_xor(l, 32);
      const float rl = 1.0f / l;
      // ---- PV: O^T[d][q] = sum_j Vt[d][j] * P^T[j][q]; P-frags built from S regs.
      f32x16 o0 = z16(), o1 = z16();
#pragma unroll
      for (int jt = 0; jt < 10; ++jt){
        unsigned P0a = pkbf(S[jt][0], S[jt][1]),  P0b = pkbf(S[jt][2], S[jt][3]);
        unsigned P1a = pkbf(S[jt][4], S[jt][5]),  P1b = pkbf(S[jt][6], S[jt][7]);
        unsigned P2a = pkbf(S[jt][8], S[jt][9]),  P2b = pkbf(S[jt][10],S[jt][11]);
        unsigned P3a = pkbf(S[jt][12],S[jt][13]), P3b = pkbf(S[jt][14],S[jt][15]);
        unsigned s0a = __shfl_xor(P0a,32), s0b = __shfl_xor(P0b,32);
        unsigned s1a = __shfl_xor(P1a,32), s1b = __shfl_xor(P1b,32);
        unsigned s2a = __shfl_xor(P2a,32), s2b = __shfl_xor(P2b,32);
        unsigned s3a = __shfl_xor(P3a,32), s3b = __shfl_xor(P3b,32);
        u32x4 fe, fo;
        if (half == 0){ fe[0]=P0a; fe[1]=P0b; fe[2]=s0a; fe[3]=s0b;
                        fo[0]=P2a; fo[1]=P2b; fo[2]=s2a; fo[3]=s2b; }
        else          { fe[0]=s1a; fe[1]=s1b; fe[2]=P1a; fe[3]=P1b;
                        fo[0]=s3a; fo[1]=s3b; fo[2]=P3a; fo[3]=P3b; }
        bf16x8 pe = __builtin_bit_cast(bf16x8, fe);
        bf16x8 po = __builtin_bit_cast(bf16x8, fo);
        bf16x8 va0e = *(const bf16x8*)(sm + VTOFF + (size_t)(     l31)*VTSTR + jt*64 + coff);
        bf16x8 va1e = *(const bf16x8*)(sm + VTOFF + (size_t)(32 + l31)*VTSTR + jt*64 + coff);
        bf16x8 va0o = *(const bf16x8*)(sm + VTOFF + (size_t)(     l31)*VTSTR + jt*64 + 32 + coff);
        bf16x8 va1o = *(const bf16x8*)(sm + VTOFF + (size_t)(32 + l31)*VTSTR + jt*64 + 32 + coff);
        o0 = MFMA32(va0e, pe, o0);
        o1 = MFMA32(va1e, pe, o1);
        o0 = MFMA32(va0o, po, o0);
        o1 = MFMA32(va1o, po, o1);
      }
      // ---- epilogue: normalize by 1/l (per-lane, q = l31 matches) and store bf16
      const size_t rowbase = (((size_t)i*NN) + q0w + l31)*INNERD + h*DH;
#pragma unroll
      for (int rq = 0; rq < 4; ++rq){
        const int dd = 8*rq + 4*half;
        uint2 v0, v1;
        v0.x = pkbf(o0[4*rq+0]*rl, o0[4*rq+1]*rl); v0.y = pkbf(o0[4*rq+2]*rl, o0[4*rq+3]*rl);
        v1.x = pkbf(o1[4*rq+0]*rl, o1[4*rq+1]*rl); v1.y = pkbf(o1[4*rq+2]*rl, o1[4*rq+3]*rl);
        *(uint2*)(AttnOut + rowbase + dd)      = v0;
        *(uint2*)(AttnOut + rowbase + 32 + dd) = v1;
      }
    }
  }
}

// ---------------------------------------------------------------------------
// Kernel B: Out = Attn @ Wout + bout.  128 rows per WG; bias folded in acc init.
// Safe when Attn aliases d_out: each WG stages its 128 rows to LDS (barrier)
// before overwriting exactly those bytes; no cross-WG overlap.
// ---------------------------------------------------------------------------
#define B_ASTR 528
#define B_WOFF 67584
#define LDS_B  135168

__global__ void __launch_bounds__(256, 1) proj_kernel(const unsigned short* __restrict__ Attn,
                                                      const float* __restrict__ Wout,
                                                      const float* __restrict__ bout,
                                                      float* __restrict__ Out){
  extern __shared__ char sm[];
  const int tid = threadIdx.x, w = tid>>6, lane = tid&63, half = lane>>5, l31 = lane&31;
  const int coff = half*16;
  const size_t r0 = (size_t)blockIdx.x * 128;
  if (tid < 128){                            // stage Wout^T [col][din] bf16
    const int col = tid;
    char* dst = sm + B_WOFF + col*B_ASTR;
    for (int d0 = 0; d0 < 256; d0 += 8){
      unsigned p0 = pkbf(Wout[(size_t)(d0+0)*128 + col], Wout[(size_t)(d0+1)*128 + col]);
      unsigned p1 = pkbf(Wout[(size_t)(d0+2)*128 + col], Wout[(size_t)(d0+3)*128 + col]);
      unsigned p2 = pkbf(Wout[(size_t)(d0+4)*128 + col], Wout[(size_t)(d0+5)*128 + col]);
      unsigned p3 = pkbf(Wout[(size_t)(d0+6)*128 + col], Wout[(size_t)(d0+7)*128 + col]);
      u32x4 v; v[0]=p0; v[1]=p1; v[2]=p2; v[3]=p3;
      *(u32x4*)(dst + d0*2) = v;
    }
  }
  {                                          // stage A tile rows r0..r0+127 (bf16 passthrough)
    const u32x4* src = (const u32x4*)(Attn + r0*INNERD);
    for (int idx = tid; idx < 4096; idx += 256){
      u32x4 v = src[idx];
      int e = idx*8, row = e >> 8, kp = e & 255;
      *(u32x4*)(sm + row*B_ASTR + kp*2) = v;
    }
  }
  __syncthreads();
  f32x16 acc[4];
#pragma unroll
  for (int nt = 0; nt < 4; ++nt){
    float bv = bout[nt*32 + l31];            // D col = output channel c
#pragma unroll
    for (int k = 0; k < 16; ++k) acc[nt][k] = bv;
  }
#pragma unroll
  for (int ks = 0; ks < 16; ++ks){
    bf16x8 a = *(const bf16x8*)(sm + (size_t)(w*32 + l31)*B_ASTR + ks*32 + coff);
#pragma unroll
    for (int nt = 0; nt < 4; ++nt){
      bf16x8 b = *(const bf16x8*)(sm + B_WOFF + (size_t)(nt*32 + l31)*B_ASTR + ks*32 + coff);
      acc[nt] = MFMA32(a, b, acc[nt]);
    }
  }
#pragma unroll
  for (int nt = 0; nt < 4; ++nt){
    const int c = nt*32 + l31;
#pragma unroll
    for (int rq = 0; rq < 4; ++rq){
#pragma unroll
      for (int r = 0; r < 4; ++r){
        const int rr = w*32 + 8*rq + 4*half + r;
        Out[(r0 + rr)*DIMD + c] = acc[nt][4*rq + r];
      }
    }
  }
}

// ---------------------------------------------------------------------------
extern "C" void kernel_launch(void* const* d_in, const int* in_sizes, int n_in,
                              void* d_out, int out_size, void* d_ws, size_t ws_size,
                              hipStream_t stream){
  const float* X     = (const float*)d_in[0];
  const float* Wqkv  = (const float*)d_in[1];
  const float* Wout  = (const float*)d_in[2];
  const float* bout  = (const float*)d_in[3];
  const float* Wbias = (const float*)d_in[4];
  float* Out = (float*)d_out;

  const size_t bias_bytes = (size_t)NHEADS*NN*NN*sizeof(float);      // 1.6 MB
  const size_t attn_bytes = (size_t)NPAIR*INNERD*2;                  // 52.4 MB bf16
  float* Bws = (float*)d_ws;                                          // requires ws >= 1.6 MB
  unsigned short* Attn = (ws_size >= bias_bytes + attn_bytes)
      ? (unsigned short*)((char*)d_ws + bias_bytes)
      : (unsigned short*)d_out;        // in-place fallback (proj_kernel is alias-safe)

  // >64 KB dynamic LDS opt-in (idempotent; set before first launch of each kernel)
  (void)hipFuncSetAttribute((const void*)attn_kernel,
                            hipFuncAttributeMaxDynamicSharedMemorySize, LDS_A);
  (void)hipFuncSetAttribute((const void*)proj_kernel,
                            hipFuncAttributeMaxDynamicSharedMemorySize, LDS_B);

  bias_kernel<<<NN, 256, 0, stream>>>(X, Wbias, Bws);
  attn_kernel<<<dim3(NHEADS, NN), 256, LDS_A, stream>>>(X, Wqkv, Bws, Attn);
  proj_kernel<<<NPAIR/128, 256, LDS_B, stream>>>(Attn, Wout, bout, Out);
}

// Round 2
// 335.312 us; speedup vs baseline: 1.2492x; 1.2492x over previous
//
#include <hip/hip_runtime.h>

// TriangleAttention (starting node), MI355X gfx950.  Round 2.
// B=1, N=320, DIM=128, HEADS=4, DH=64, INNER=256. fp32 I/O, bf16 MFMA inside.
//
// Pipeline:
//  x2bf_bias: one wave per (q,k) pair: X fp32 -> Xbf (bf16, ws) + fp32 bias GEMV
//             Bws[h][q][k] (wave shfl-reduce).
//  wpack:     Wqkv fp32 -> Wqkvt bf16 [col 768][din 128] (ws).
//  attn:      per (h,i), 512 thr / 8 waves, 2 waves/SIMD. LDS: K,Vt,W only (140 KB).
//             Phase 1: 20 barrier-free wave-tasks build K/Vt (frags direct from Xbf).
//             Phase 2: 10 barrier-free q-tile tasks: Q-proj (D->B-frag in-register via
//             shfl_xor(32)), scores^T, lane-local softmax (+float4 bias), PV with
//             register-built P-frags. Only 2 __syncthreads total.
//  proj:      Out = Attn @ Wout + bout. Attn bf16 lives IN d_out; each wave reads its
//             own 32 rows then overwrites them (alias-safe, no A staging, 2 WG/CU).

#define NN     320
#define DIMD   128
#define NHEADS 4
#define DH     64
#define INNERD 256
#define NPAIR  (NN*NN)
#define SCALE  0.125f

typedef __attribute__((ext_vector_type(8)))  short    bf16x8;
typedef __attribute__((ext_vector_type(16))) float    f32x16;
typedef __attribute__((ext_vector_type(4)))  unsigned u32x4;

#define MFMA32(a,b,c) __builtin_amdgcn_mfma_f32_32x32x16_bf16((a),(b),(c),0,0,0)

__device__ __forceinline__ unsigned pkbf(float lo, float hi){
  unsigned a = __builtin_bit_cast(unsigned, lo);
  unsigned b = __builtin_bit_cast(unsigned, hi);
  a = (a + 0x7fffu + ((a>>16)&1u)) >> 16;
  b = (b + 0x7fffu + ((b>>16)&1u)) >> 16;
  return (a & 0xffffu) | (b<<16);
}
__device__ __forceinline__ unsigned short bf1(float f){
  unsigned u = __builtin_bit_cast(unsigned, f);
  return (unsigned short)((u + 0x7fffu + ((u>>16)&1u)) >> 16);
}
__device__ __forceinline__ f32x16 z16(){
  f32x16 v;
#pragma unroll
  for (int k = 0; k < 16; ++k) v[k] = 0.0f;
  return v;
}

// ---------------------------------------------------------------------------
// x2bf_bias: wave per pair p=(q,k). Read 128 fp32 (float2/lane), write 64 dwords
// bf16 (XBF), and 4-head bias dot via fp32 shfl-reduce into Bws[h][q][k].
// ---------------------------------------------------------------------------
template<bool XBF>
__global__ void __launch_bounds__(256) x2bf_bias(const float* __restrict__ X,
                                                 const float* __restrict__ Wbias,
                                                 float* __restrict__ Bws,
                                                 unsigned* __restrict__ XbfU){
  const int tid  = threadIdx.x;
  const int lane = tid & 63;
  const int p    = blockIdx.x*4 + (tid >> 6);
  const int q    = p / NN, k = p - q*NN;
  float2 v = ((const float2*)(X + (size_t)p*DIMD))[lane];
  float4 w0 = ((const float4*)Wbias)[2*lane];
  float4 w1 = ((const float4*)Wbias)[2*lane+1];
  float4 s;
  s.x = v.x*w0.x + v.y*w1.x;
  s.y = v.x*w0.y + v.y*w1.y;
  s.z = v.x*w0.z + v.y*w1.z;
  s.w = v.x*w0.w + v.y*w1.w;
  if (XBF) XbfU[(size_t)p*64 + lane] = pkbf(v.x, v.y);
#pragma unroll
  for (int off = 32; off >= 1; off >>= 1){
    s.x += __shfl_xor(s.x, off);
    s.y += __shfl_xor(s.y, off);
    s.z += __shfl_xor(s.z, off);
    s.w += __shfl_xor(s.w, off);
  }
  if (lane == 0){
    Bws[(size_t)0*NPAIR + q*NN + k] = s.x;
    Bws[(size_t)1*NPAIR + q*NN + k] = s.y;
    Bws[(size_t)2*NPAIR + q*NN + k] = s.z;
    Bws[(size_t)3*NPAIR + q*NN + k] = s.w;
  }
}

// ---------------------------------------------------------------------------
// wpack: Wqkvt[c*128+d] = bf16(Wqkv[d*768+c]).  Coalesced reads, tiny scatter.
// ---------------------------------------------------------------------------
__global__ void __launch_bounds__(256) wpack(const float* __restrict__ Wqkv,
                                             unsigned short* __restrict__ Wqkvt){
  const int idx = blockIdx.x*256 + threadIdx.x;   // < 98304
  const int c = idx % 768, d = idx / 768;
  Wqkvt[c*DIMD + d] = bf1(Wqkv[idx]);
}

// ---------------------------------------------------------------------------
// attn kernel.  LDS map (bytes):
//   K   [320 j][64 d]  stride 144 :      0 ..  46080
//   Vt  [64 d][320 j]  stride 656 :  46080 ..  88064
//   W   [192 col][128 din] str 272:  88064 .. 140288   (q:0-63, k:64-127, v:128-191)
// ---------------------------------------------------------------------------
#define KOFF   0
#define VTOFF  46080
#define WOFF   88064
#define LDS_A  140288
#define KSTR   144
#define VTSTR  656
#define WSTR   272

template<bool XBF>
__device__ __forceinline__ bf16x8 xfrag(const float* Xf, const unsigned short* Xb,
                                        int row, int ks, int coff, int half){
  if constexpr (XBF){
    return *(const bf16x8*)((const char*)Xb + (size_t)row*256 + ks*32 + coff);
  } else {
    const float* p = Xf + (size_t)row*DIMD + ks*16 + half*8;
    float4 x0 = ((const float4*)p)[0], x1 = ((const float4*)p)[1];
    u32x4 v; v[0]=pkbf(x0.x,x0.y); v[1]=pkbf(x0.z,x0.w); v[2]=pkbf(x1.x,x1.y); v[3]=pkbf(x1.z,x1.w);
    return __builtin_bit_cast(bf16x8, v);
  }
}

template<bool XBF>
__global__ void __launch_bounds__(512, 2) attn_kernel(const float* __restrict__ X,
                                                      const unsigned short* __restrict__ Xbf,
                                                      const float* __restrict__ Wqkv,
                                                      const unsigned short* __restrict__ Wqkvt,
                                                      const float* __restrict__ Bws,
                                                      unsigned short* __restrict__ AttnOut){
  extern __shared__ char sm[];
  const int h = blockIdx.x, i = blockIdx.y;
  const int tid  = threadIdx.x;
  const int w    = tid >> 6;
  const int lane = tid & 63;
  const int half = lane >> 5;
  const int l31  = lane & 31;
  const int coff = half*16;

  // ---- stage W (q|k|v cols for this head), transposed [col][din] bf16
  if (XBF){
    for (int idx = tid; idx < 192*16; idx += 512){
      const int col = idx >> 4, seg = idx & 15;
      const int gcol = (col < 64)  ? (h*DH + col)
                     : (col < 128) ? (INNERD   + h*DH + (col-64))
                                   : (2*INNERD + h*DH + (col-128));
      u32x4 v = *(const u32x4*)(Wqkvt + (size_t)gcol*DIMD + seg*8);
      *(u32x4*)(sm + WOFF + (size_t)col*WSTR + seg*16) = v;
    }
  } else if (tid < 192){
    const int col  = tid;
    const int gcol = (col < 64)  ? (h*DH + col)
                   : (col < 128) ? (INNERD   + h*DH + (col-64))
                                 : (2*INNERD + h*DH + (col-128));
    char* dst = sm + WOFF + (size_t)col*WSTR;
    for (int d0 = 0; d0 < DIMD; d0 += 8){
      u32x4 v;
      v[0] = pkbf(Wqkv[(size_t)(d0+0)*768 + gcol], Wqkv[(size_t)(d0+1)*768 + gcol]);
      v[1] = pkbf(Wqkv[(size_t)(d0+2)*768 + gcol], Wqkv[(size_t)(d0+3)*768 + gcol]);
      v[2] = pkbf(Wqkv[(size_t)(d0+4)*768 + gcol], Wqkv[(size_t)(d0+5)*768 + gcol]);
      v[3] = pkbf(Wqkv[(size_t)(d0+6)*768 + gcol], Wqkv[(size_t)(d0+7)*768 + gcol]);
      *(u32x4*)(dst + d0*2) = v;
    }
  }
  __syncthreads();

  // ================= phase 1: 20 barrier-free wave-tasks (10 K, 10 V) ==========
  for (int r = 0; r < 3; ++r){
    const int t = w + 8*r;
    if (t >= 20) break;
    const bool isK = (t < 10);
    const int  jt  = isK ? t : t - 10;
    const int  jrow = jt*32 + l31;
    const int  grow = i*NN + jrow;
    f32x16 acc0 = z16(), acc1 = z16();
    if (isK){
      const char* A0 = sm + WOFF + (size_t)(64 + l31)*WSTR;
      const char* A1 = sm + WOFF + (size_t)(96 + l31)*WSTR;
#pragma unroll
      for (int ks = 0; ks < 8; ++ks){
        bf16x8 b  = xfrag<XBF>(X, Xbf, grow, ks, coff, half);
        bf16x8 a0 = *(const bf16x8*)(A0 + ks*32 + coff);
        bf16x8 a1 = *(const bf16x8*)(A1 + ks*32 + coff);
        acc0 = MFMA32(a0, b, acc0);
        acc1 = MFMA32(a1, b, acc1);
      }
#pragma unroll
      for (int rq = 0; rq < 4; ++rq){
        uint2 v0, v1;
        v0.x = pkbf(acc0[4*rq+0], acc0[4*rq+1]); v0.y = pkbf(acc0[4*rq+2], acc0[4*rq+3]);
        v1.x = pkbf(acc1[4*rq+0], acc1[4*rq+1]); v1.y = pkbf(acc1[4*rq+2], acc1[4*rq+3]);
        *(uint2*)(sm + KOFF + (size_t)jrow*KSTR +      (8*rq + 4*half)*2) = v0;
        *(uint2*)(sm + KOFF + (size_t)jrow*KSTR + 64 + (8*rq + 4*half)*2) = v1;
      }
    } else {
      const char* B0 = sm + WOFF + (size_t)(128 + l31)*WSTR;
      const char* B1 = sm + WOFF + (size_t)(160 + l31)*WSTR;
#pragma unroll
      for (int ks = 0; ks < 8; ++ks){
        bf16x8 a  = xfrag<XBF>(X, Xbf, grow, ks, coff, half);
        bf16x8 b0 = *(const bf16x8*)(B0 + ks*32 + coff);
        bf16x8 b1 = *(const bf16x8*)(B1 + ks*32 + coff);
        acc0 = MFMA32(a, b0, acc0);
        acc1 = MFMA32(a, b1, acc1);
      }
#pragma unroll
      for (int rq = 0; rq < 4; ++rq){
        uint2 v0, v1;
        v0.x = pkbf(acc0[4*rq+0], acc0[4*rq+1]); v0.y = pkbf(acc0[4*rq+2], acc0[4*rq+3]);
        v1.x = pkbf(acc1[4*rq+0], acc1[4*rq+1]); v1.y = pkbf(acc1[4*rq+2], acc1[4*rq+3]);
        *(uint2*)(sm + VTOFF + (size_t)(     l31)*VTSTR + (jt*32 + 8*rq + 4*half)*2) = v0;
        *(uint2*)(sm + VTOFF + (size_t)(32 + l31)*VTSTR + (jt*32 + 8*rq + 4*half)*2) = v1;
      }
    }
  }
  __syncthreads();

  // ================= phase 2: 10 barrier-free q-tile wave-tasks ===============
  for (int rep = 0; rep < 2; ++rep){
    const int qt = w + 8*rep;
    if (qt >= 10) break;
    const int q = qt*32 + l31;
    // ---- Q-proj: D col = q, rows = d
    f32x16 qa0 = z16(), qa1 = z16();
#pragma unroll
    for (int ks = 0; ks < 8; ++ks){
      bf16x8 b  = xfrag<XBF>(X, Xbf, i*NN + q, ks, coff, half);
      bf16x8 a0 = *(const bf16x8*)(sm + WOFF + (size_t)(     l31)*WSTR + ks*32 + coff);
      bf16x8 a1 = *(const bf16x8*)(sm + WOFF + (size_t)(32 + l31)*WSTR + ks*32 + coff);
      qa0 = MFMA32(a0, b, qa0);
      qa1 = MFMA32(a1, b, qa1);
    }
    // ---- build qf[4] (B-frags over d) in-register from D-layout via shfl_xor(32)
    bf16x8 qf[4];
    {
      unsigned a0 = pkbf(qa0[0],qa0[1]),  a0b = pkbf(qa0[2],qa0[3]);
      unsigned a1 = pkbf(qa0[4],qa0[5]),  a1b = pkbf(qa0[6],qa0[7]);
      unsigned a2 = pkbf(qa0[8],qa0[9]),  a2b = pkbf(qa0[10],qa0[11]);
      unsigned a3 = pkbf(qa0[12],qa0[13]),a3b = pkbf(qa0[14],qa0[15]);
      unsigned b0 = pkbf(qa1[0],qa1[1]),  b0b = pkbf(qa1[2],qa1[3]);
      unsigned b1 = pkbf(qa1[4],qa1[5]),  b1b = pkbf(qa1[6],qa1[7]);
      unsigned b2 = pkbf(qa1[8],qa1[9]),  b2b = pkbf(qa1[10],qa1[11]);
      unsigned b3 = pkbf(qa1[12],qa1[13]),b3b = pkbf(qa1[14],qa1[15]);
      unsigned sa0=__shfl_xor(a0,32), sa0b=__shfl_xor(a0b,32);
      unsigned sa1=__shfl_xor(a1,32), sa1b=__shfl_xor(a1b,32);
      unsigned sa2=__shfl_xor(a2,32), sa2b=__shfl_xor(a2b,32);
      unsigned sa3=__shfl_xor(a3,32), sa3b=__shfl_xor(a3b,32);
      unsigned sb0=__shfl_xor(b0,32), sb0b=__shfl_xor(b0b,32);
      unsigned sb1=__shfl_xor(b1,32), sb1b=__shfl_xor(b1b,32);
      unsigned sb2=__shfl_xor(b2,32), sb2b=__shfl_xor(b2b,32);
      unsigned sb3=__shfl_xor(b3,32), sb3b=__shfl_xor(b3b,32);
      u32x4 f;
      if (half == 0){
        f[0]=a0; f[1]=a0b; f[2]=sa0; f[3]=sa0b; qf[0]=__builtin_bit_cast(bf16x8,f);
        f[0]=a2; f[1]=a2b; f[2]=sa2; f[3]=sa2b; qf[1]=__builtin_bit_cast(bf16x8,f);
        f[0]=b0; f[1]=b0b; f[2]=sb0; f[3]=sb0b; qf[2]=__builtin_bit_cast(bf16x8,f);
        f[0]=b2; f[1]=b2b; f[2]=sb2; f[3]=sb2b; qf[3]=__builtin_bit_cast(bf16x8,f);
      } else {
        f[0]=sa1; f[1]=sa1b; f[2]=a1; f[3]=a1b; qf[0]=__builtin_bit_cast(bf16x8,f);
        f[0]=sa3; f[1]=sa3b; f[2]=a3; f[3]=a3b; qf[1]=__builtin_bit_cast(bf16x8,f);
        f[0]=sb1; f[1]=sb1b; f[2]=b1; f[3]=b1b; qf[2]=__builtin_bit_cast(bf16x8,f);
        f[0]=sb3; f[1]=sb3b; f[2]=b3; f[3]=b3b; qf[3]=__builtin_bit_cast(bf16x8,f);
      }
    }
    // ---- scores^T: S[j][q], D col = q = l31, rows = j
    f32x16 S[10];
#pragma unroll
    for (int jt = 0; jt < 10; ++jt) S[jt] = z16();
#pragma unroll
    for (int jt = 0; jt < 10; ++jt){
#pragma unroll
      for (int c = 0; c < 4; ++c){
        bf16x8 a = *(const bf16x8*)(sm + KOFF + (size_t)(jt*32 + l31)*KSTR + c*32 + coff);
        S[jt] = MFMA32(a, qf[c], S[jt]);
      }
    }
    // ---- scale + bias (float4 per rq) + softmax over j
    const float4* Bf = (const float4*)(Bws + (size_t)h*NPAIR + (size_t)q*NN);
    float m = -3.0e38f;
#pragma unroll
    for (int jt = 0; jt < 10; ++jt){
#pragma unroll
      for (int rq = 0; rq < 4; ++rq){
        float4 bv = Bf[jt*8 + 2*rq + half];
        float v0 = S[jt][4*rq+0]*SCALE + bv.x;
        float v1 = S[jt][4*rq+1]*SCALE + bv.y;
        float v2 = S[jt][4*rq+2]*SCALE + bv.z;
        float v3 = S[jt][4*rq+3]*SCALE + bv.w;
        S[jt][4*rq+0]=v0; S[jt][4*rq+1]=v1; S[jt][4*rq+2]=v2; S[jt][4*rq+3]=v3;
        m = fmaxf(m, fmaxf(fmaxf(v0,v1), fmaxf(v2,v3)));
      }
    }
    m = fmaxf(m, __shfl_xor(m, 32));
    float l = 0.0f;
#pragma unroll
    for (int jt = 0; jt < 10; ++jt){
#pragma unroll
      for (int k = 0; k < 16; ++k){
        float e = __expf(S[jt][k] - m);
        S[jt][k] = e;
        l += e;
      }
    }
    l += __shfl_xor(l, 32);
    const float rl = 1.0f / l;
    // ---- PV: O^T[d][q] += Vt[d][j] * P^T[j][q]; P-frags from S regs via shfl.
    f32x16 o0 = z16(), o1 = z16();
#pragma unroll
    for (int jt = 0; jt < 10; ++jt){
      unsigned P0a = pkbf(S[jt][0], S[jt][1]),  P0b = pkbf(S[jt][2], S[jt][3]);
      unsigned P1a = pkbf(S[jt][4], S[jt][5]),  P1b = pkbf(S[jt][6], S[jt][7]);
      unsigned P2a = pkbf(S[jt][8], S[jt][9]),  P2b = pkbf(S[jt][10],S[jt][11]);
      unsigned P3a = pkbf(S[jt][12],S[jt][13]), P3b = pkbf(S[jt][14],S[jt][15]);
      unsigned s0a = __shfl_xor(P0a,32), s0b = __shfl_xor(P0b,32);
      unsigned s1a = __shfl_xor(P1a,32), s1b = __shfl_xor(P1b,32);
      unsigned s2a = __shfl_xor(P2a,32), s2b = __shfl_xor(P2b,32);
      unsigned s3a = __shfl_xor(P3a,32), s3b = __shfl_xor(P3b,32);
      u32x4 fe, fo;
      if (half == 0){ fe[0]=P0a; fe[1]=P0b; fe[2]=s0a; fe[3]=s0b;
                      fo[0]=P2a; fo[1]=P2b; fo[2]=s2a; fo[3]=s2b; }
      else          { fe[0]=s1a; fe[1]=s1b; fe[2]=P1a; fe[3]=P1b;
                      fo[0]=s3a; fo[1]=s3b; fo[2]=P3a; fo[3]=P3b; }
      bf16x8 pe = __builtin_bit_cast(bf16x8, fe);
      bf16x8 po = __builtin_bit_cast(bf16x8, fo);
      bf16x8 va0e = *(const bf16x8*)(sm + VTOFF + (size_t)(     l31)*VTSTR + jt*64 + coff);
      bf16x8 va1e = *(const bf16x8*)(sm + VTOFF + (size_t)(32 + l31)*VTSTR + jt*64 + coff);
      bf16x8 va0o = *(const bf16x8*)(sm + VTOFF + (size_t)(     l31)*VTSTR + jt*64 + 32 + coff);
      bf16x8 va1o = *(const bf16x8*)(sm + VTOFF + (size_t)(32 + l31)*VTSTR + jt*64 + 32 + coff);
      o0 = MFMA32(va0e, pe, o0);
      o1 = MFMA32(va1e, pe, o1);
      o0 = MFMA32(va0o, po, o0);
      o1 = MFMA32(va1o, po, o1);
    }
    // ---- epilogue
    const size_t rowbase = (((size_t)i*NN) + q)*INNERD + h*DH;
#pragma unroll
    for (int rq = 0; rq < 4; ++rq){
      const int dd = 8*rq + 4*half;
      uint2 v0, v1;
      v0.x = pkbf(o0[4*rq+0]*rl, o0[4*rq+1]*rl); v0.y = pkbf(o0[4*rq+2]*rl, o0[4*rq+3]*rl);
      v1.x = pkbf(o1[4*rq+0]*rl, o1[4*rq+1]*rl); v1.y = pkbf(o1[4*rq+2]*rl, o1[4*rq+3]*rl);
      *(uint2*)(AttnOut + rowbase + dd)      = v0;
      *(uint2*)(AttnOut + rowbase + 32 + dd) = v1;
    }
  }
}

// ---------------------------------------------------------------------------
// proj: Out = Attn @ Wout + bout.  LDS = W^T only (67.6 KB -> 2 WG/CU).
// A-frags straight from global; wave reads exactly the 32 rows it later writes
// (program-order read-before-write => alias-safe with Attn in d_out).
// ---------------------------------------------------------------------------
#define B_WSTR 528
#define LDS_P  67584

__global__ void __launch_bounds__(256, 2) proj_kernel(const unsigned short* Attn,
                                                      const float* __restrict__ Wout,
                                                      const float* __restrict__ bout,
                                                      float* Out){
  extern __shared__ char sm[];
  const int tid = threadIdx.x, w = tid>>6, lane = tid&63, half = lane>>5, l31 = lane&31;
  const int coff = half*16;
  const size_t r0 = (size_t)blockIdx.x * 128;
  if (tid < 128){                            // stage Wout^T [col][din] bf16
    const int col = tid;
    char* dst = sm + (size_t)col*B_WSTR;
    for (int d0 = 0; d0 < 256; d0 += 8){
      u32x4 v;
      v[0] = pkbf(Wout[(size_t)(d0+0)*DIMD + col], Wout[(size_t)(d0+1)*DIMD + col]);
      v[1] = pkbf(Wout[(size_t)(d0+2)*DIMD + col], Wout[(size_t)(d0+3)*DIMD + col]);
      v[2] = pkbf(Wout[(size_t)(d0+4)*DIMD + col], Wout[(size_t)(d0+5)*DIMD + col]);
      v[3] = pkbf(Wout[(size_t)(d0+6)*DIMD + col], Wout[(size_t)(d0+7)*DIMD + col]);
      *(u32x4*)(dst + d0*2) = v;
    }
  }
  __syncthreads();
  f32x16 acc[4];
#pragma unroll
  for (int nt = 0; nt < 4; ++nt){
    float bv = bout[nt*32 + l31];
#pragma unroll
    for (int k = 0; k < 16; ++k) acc[nt][k] = bv;
  }
  const char* Ab = (const char*)Attn + (r0 + w*32 + l31)*512;
#pragma unroll
  for (int ks = 0; ks < 16; ++ks){
    bf16x8 a = *(const bf16x8*)(Ab + ks*32 + coff);
#pragma unroll
    for (int nt = 0; nt < 4; ++nt){
      bf16x8 b = *(const bf16x8*)(sm + (size_t)(nt*32 + l31)*B_WSTR + ks*32 + coff);
      acc[nt] = MFMA32(a, b, acc[nt]);
    }
  }
#pragma unroll
  for (int nt = 0; nt < 4; ++nt){
    const int c = nt*32 + l31;
#pragma unroll
    for (int rq = 0; rq < 4; ++rq){
#pragma unroll
      for (int r = 0; r < 4; ++r){
        const int rr = w*32 + 8*rq + 4*half + r;
        Out[(r0 + rr)*DIMD + c] = acc[nt][4*rq + r];
      }
    }
  }
}

// ---------------------------------------------------------------------------
extern "C" void kernel_launch(void* const* d_in, const int* in_sizes, int n_in,
                              void* d_out, int out_size, void* d_ws, size_t ws_size,
                              hipStream_t stream){
  const float* X     = (const float*)d_in[0];
  const float* Wqkv  = (const float*)d_in[1];
  const float* Wout  = (const float*)d_in[2];
  const float* bout  = (const float*)d_in[3];
  const float* Wbias = (const float*)d_in[4];
  float* Out = (float*)d_out;

  // ws layout: Bws fp32 [0,1638400) | Xbf bf16 [1638400,27852800) | Wqkvt [.., 28049408)
  float*          Bws   = (float*)d_ws;
  unsigned short* Xbf   = (unsigned short*)((char*)d_ws + 1638400);
  unsigned*       XbfU  = (unsigned*)Xbf;
  unsigned short* Wqkvt = (unsigned short*)((char*)d_ws + 27852800);
  const bool use_bf = (ws_size >= (size_t)28049408);

  unsigned short* Attn = (unsigned short*)d_out;   // bf16 intermediate lives in d_out

  (void)hipFuncSetAttribute((const void*)proj_kernel,
                            hipFuncAttributeMaxDynamicSharedMemorySize, LDS_P);
  if (use_bf){
    (void)hipFuncSetAttribute((const void*)attn_kernel<true>,
                              hipFuncAttributeMaxDynamicSharedMemorySize, LDS_A);
    x2bf_bias<true><<<NPAIR/4, 256, 0, stream>>>(X, Wbias, Bws, XbfU);
    wpack<<<768*DIMD/256, 256, 0, stream>>>(Wqkv, Wqkvt);
    attn_kernel<true><<<dim3(NHEADS, NN), 512, LDS_A, stream>>>(X, Xbf, Wqkv, Wqkvt, Bws, Attn);
  } else {
    (void)hipFuncSetAttribute((const void*)attn_kernel<false>,
                              hipFuncAttributeMaxDynamicSharedMemorySize, LDS_A);
    x2bf_bias<false><<<NPAIR/4, 256, 0, stream>>>(X, Wbias, Bws, nullptr);
    attn_kernel<false><<<dim3(NHEADS, NN), 512, LDS_A, stream>>>(X, nullptr, Wqkv, nullptr, Bws, Attn);
  }
  proj_kernel<<<NPAIR/128, 256, LDS_P, stream>>>(Attn, Wout, bout, Out);
}